// Round 16
// baseline (61.226 us; speedup 1.0000x reference)
//
#include <hip/hip_runtime.h>

// AUAvULoss: probs[N,8], y[N,8] one-hot, weights[N,8] -> (avu_loss, CE_loss)
//
// R16 = R13/R15 structure + the waves/CU lever (the one empirically-scaling
// variable: R7's 32-waves/CU config delivered 4.2-5 TB/s vs 2.3 at 16).
//   * grid 1024 x 512 -> 4 blocks/CU x 8 waves = 32 waves/CU ceiling
//   * 2-ROW fine hist (base-sums for correct/incorrect only); tanh applied at
//     BIN CENTER in the tail (err <= 2.1e-3 on weights -> ~6e-3 on out[0],
//     8x under the 4.97e-2 threshold). Removes per-sample tanhf (VGPR down,
//     R14's 64-VGPR cliff avoided), halves LDS hist to 16.4 KB (fits 4
//     blocks/CU), single lane-atomic per sample.
//   * GREP 32 -> flush chains <= 32 despite 1024 blocks.
// Exonerated by measurement: lane coalescing (R4), stream batching (R5),
// LDS-atomic contention (R15 null), compute thinning (R8 null), grid shape
// at fixed 16 waves/CU (R14). NO in-kernel cross-block waiting (R3/R12).

constexpr int C     = 8;
constexpr int NTH   = 21;
constexpr int NB    = 22;       // 0..20 = first threshold satisfied; 21 = none
constexpr int NFINE = 512;      // fine bins over [0, ln8]
constexpr int NROW  = 2;        // base-sum rows: 0=correct, 1=incorrect
constexpr int GREP  = 32;       // global fine-hist replicas (chains <= 32)
constexpr int NBLK  = 1024;
constexpr int BS    = 512;
constexpr int LREP  = 4;        // LDS hist replicas
constexpr int ROWSTR = NFINE + 1;        // 513 (odd -> bank rotation)
constexpr int REPSTR = NROW * ROWSTR;    // 1026 floats per replica
constexpr float UHI      = 2.0794415416798357f;   // ln(8): entropy upper bound
constexpr float INVW     = (float)NFINE / UHI;
constexpr float BINW     = UHI / (float)NFINE;
constexpr float LOG_FEPS = -18.420680743952367f;  // logf(1e-8f)

struct Accum {
  int   done; int dpad[63];
  float f_part[NBLK], c_part[NBLK], mn_part[NBLK], mx_part[NBLK];
  float ghist[GREP][NROW * NFINE];
};

__global__ __launch_bounds__(256) void init_k(Accum* acc) {
  if (threadIdx.x == 0) acc->done = 0;
  for (int i = threadIdx.x; i < GREP * NROW * NFINE; i += 256)
    ((float*)acc->ghist)[i] = 0.f;
}

// Branchless first-satisfied-threshold (same float expr as reference).
__device__ __forceinline__ int bin_of(float u, float umin, float scale) {
  int t0 = NB - 1;
#pragma unroll
  for (int t = NTH - 1; t >= 0; --t) {
    float thr = umin + ((float)t * 0.05f) * scale;
    if (u <= thr) t0 = t;                 // cndmask, no branch
  }
  return t0;
}

__device__ __forceinline__ void epilogue(const float* hist, double fsum, double csum,
                                         float* out, int N) {
  const float *hac = &hist[0], *hau = &hist[NB], *hic = &hist[2 * NB], *hiu = &hist[3 * NB];
  float tot_au = 0.f, tot_iu = 0.f;
  for (int s = 0; s < NB; ++s) { tot_au += hau[s]; tot_iu += hiu[s]; }
  float pac = 0.f, pau = 0.f, pic = 0.f, piu = 0.f, auc = 0.f, prev = 0.f;
  for (int t = 0; t < NTH; ++t) {
    pac += hac[t]; pau += hau[t]; pic += hic[t]; piu += hiu[t];
    float n_ac = pac, n_au = tot_au - pau, n_ic = pic, n_iu = tot_iu - piu;
    float avu = (n_ac + n_iu) / (n_ac + n_au + n_ic + n_iu + 1e-10f);
    if (t > 0) auc += 0.5f * (avu + prev) * 0.05f;
    prev = avu;
  }
  out[0] = -logf(auc + 1e-10f) + (float)(fsum / (double)N);  // BETA = 1
  out[1] = (float)(csum / (double)N);
}

__device__ __forceinline__ float agent_ldf(const float* p) {
  return __hip_atomic_load(p, __ATOMIC_RELAXED, __HIP_MEMORY_SCOPE_AGENT);
}

__global__ __launch_bounds__(BS) void pass1f_k(const float4* __restrict__ p4,
                                               const float4* __restrict__ y4,
                                               const float4* __restrict__ w4,
                                               const float*  __restrict__ yraw,
                                               Accum* __restrict__ acc,
                                               float* __restrict__ out, int N) {
  __shared__ float h[LREP * REPSTR];        // 16.4 KB: 4 replicas x 2 rows x 513
  __shared__ int sh_l0;
  for (int i = threadIdx.x; i < LREP * REPSTR; i += BS) h[i] = 0.f;
  if (threadIdx.x == 0) {
    float best = yraw[0]; int bi = 0;
#pragma unroll
    for (int j = 1; j < C; ++j) { if (yraw[j] > best) { best = yraw[j]; bi = j; } }
    sh_l0 = bi;
  }
  __syncthreads();
  const int l0   = sh_l0;
  const int tid  = threadIdx.x;
  const int q    = tid & 1;                 // channel half (0: ch0-3, 1: ch4-7)
  const int T    = blockIdx.x * BS + tid;
  const int S    = NBLK * BS;
  const int twoN = 2 * N;                   // f4s per array (even; pairs intact)
  float* const hrep = &h[((tid >> 1) & (LREP - 1)) * REPSTR];

  float fsum = 0.f, csum = 0.f;
  float umin = __uint_as_float(0x7F800000u), umax = 0.f;

  for (int idx = T; idx < twoN; idx += S) {
    float4 pv = p4[idx];
    float4 yv = y4[idx];
    float4 wv = w4[idx];
    float P[4] = {pv.x, pv.y, pv.z, pv.w};
    float Y[4] = {yv.x, yv.y, yv.z, yv.w};
    float W[4] = {wv.x, wv.y, wv.z, wv.w};
    float up = 0.f, cep = 0.f, fop = 0.f;
    float cmax = P[0]; int pid = 0;
#pragma unroll
    for (int j = 0; j < 4; ++j) {
      if (j > 0 && P[j] > cmax) { cmax = P[j]; pid = j; }  // first-occurrence
      float le = __logf(fmaxf(P[j], 1e-10f));              // entropy log (EPS=1e-10)
      up -= P[j] * le;
      float lf = fmaxf(le, LOG_FEPS);                      // = log(max(p,1e-8))
      float t  = Y[j] * lf;
      cep -= t; fop -= t * W[j];
    }
    pid += 4 * q;
    fsum += fop; csum += cep;               // each lane adds its own half
    float unc = up + __shfl_xor(up, 1);     // symmetric: both lanes identical
    float oc  = __shfl_xor(cmax, 1);
    int   op  = __shfl_xor(pid, 1);
    float lo_c = q ? oc : cmax;  int lo_p = q ? op : pid;
    float hi_c = q ? cmax : oc;  int hi_p = q ? pid : op;
    float conf = (hi_c > lo_c) ? hi_c : lo_c;   // ties -> low half (first occ.)
    int   pred = (hi_c > lo_c) ? hi_p : lo_p;
    umin = fminf(umin, unc); umax = fmaxf(umax, unc);
    if (q == 0) {                           // even lane owns the sample
      bool  corr = (pred == l0);
      float base = corr ? conf : (1.f - conf);
      int   b    = (int)(unc * INVW); b = b < NFINE - 1 ? b : NFINE - 1;
      int   row  = corr ? 0 : 1;            // base-sum only; tanh in tail
      atomicAdd(&hrep[row * ROWSTR + b], base);
    }
  }

  {  // per-block partials
    float v0 = fsum, v1 = csum, v2 = umin, v3 = umax;
#pragma unroll
    for (int o = 32; o > 0; o >>= 1) {
      v0 += __shfl_down(v0, o); v1 += __shfl_down(v1, o);
      v2 = fminf(v2, __shfl_down(v2, o)); v3 = fmaxf(v3, __shfl_down(v3, o));
    }
    __shared__ float r0[BS / 64], r1[BS / 64], r2[BS / 64], r3[BS / 64];
    int ln = tid & 63, wd = tid >> 6;
    if (ln == 0) { r0[wd] = v0; r1[wd] = v1; r2[wd] = v2; r3[wd] = v3; }
    __syncthreads();
    if (tid == 0) {
      float a0 = r0[0], a1 = r1[0], a2 = r2[0], a3 = r3[0];
#pragma unroll
      for (int wv = 1; wv < BS / 64; ++wv) {
        a0 += r0[wv]; a1 += r1[wv];
        a2 = fminf(a2, r2[wv]); a3 = fmaxf(a3, r3[wv]);
      }
      acc->f_part[blockIdx.x] = a0;  acc->c_part[blockIdx.x] = a1;
      acc->mn_part[blockIdx.x] = a2; acc->mx_part[blockIdx.x] = a3;
    }
  }
  __syncthreads();
  // flush: sum 4 LDS replicas per (row,bin), skip zeros, one global atomic
  for (int i = tid; i < NROW * NFINE; i += BS) {
    int row = i >> 9, bin = i & (NFINE - 1);
    float v = 0.f;
#pragma unroll
    for (int r = 0; r < LREP; ++r) v += h[r * REPSTR + row * ROWSTR + bin];
    if (v != 0.f) atomicAdd(&acc->ghist[blockIdx.x & (GREP - 1)][i], v);
  }

  // retirement counter (NO waiting: only the last arriver proceeds)
  __shared__ int amLast;
  __syncthreads();
  if (tid == 0) {
    __threadfence();
    amLast = (atomicAdd(&acc->done, 1) == (int)gridDim.x - 1);
  }
  __syncthreads();
  if (!amLast) return;

  // ---------------- tail (last block only) ----------------
  __threadfence();
  __shared__ float sh_umin, sh_scale;
  __shared__ double df[BS / 64], dc[BS / 64];
  {
    float mn = __uint_as_float(0x7F800000u), mx = 0.f;
    double f = 0.0, c = 0.0;
    for (int i = tid; i < NBLK; i += BS) {
      mn = fminf(mn, agent_ldf(&acc->mn_part[i]));
      mx = fmaxf(mx, agent_ldf(&acc->mx_part[i]));
      f += (double)agent_ldf(&acc->f_part[i]);
      c += (double)agent_ldf(&acc->c_part[i]);
    }
#pragma unroll
    for (int o = 32; o > 0; o >>= 1) {
      mn = fminf(mn, __shfl_down(mn, o)); mx = fmaxf(mx, __shfl_down(mx, o));
      f += __shfl_down(f, o);             c += __shfl_down(c, o);
    }
    __shared__ float rmn[BS / 64], rmx[BS / 64];
    int ln = tid & 63, wd = tid >> 6;
    if (ln == 0) { rmn[wd] = mn; rmx[wd] = mx; df[wd] = f; dc[wd] = c; }
    __syncthreads();
    if (tid == 0) {
      float a = rmn[0], b = rmx[0];
#pragma unroll
      for (int wv = 1; wv < BS / 64; ++wv) { a = fminf(a, rmn[wv]); b = fmaxf(b, rmx[wv]); }
      sh_umin = a; sh_scale = b - a;
    }
    __syncthreads();
  }
  const float gumin = sh_umin, gscale = sh_scale;

  // fine -> coarse (each thread owns one fine bin; NFINE == BS)
  __shared__ float coarse[4 * NB];
  if (tid < 4 * NB) coarse[tid] = 0.f;
  __syncthreads();
  {
    int f = tid & (NFINE - 1);              // NFINE == BS exactly
    float bc = 0.f, bi = 0.f;
#pragma unroll
    for (int r = 0; r < GREP; ++r) {
      bc += agent_ldf(&acc->ghist[r][0 * NFINE + f]);
      bi += agent_ldf(&acc->ghist[r][1 * NFINE + f]);
    }
    float cf = ((float)f + 0.5f) * BINW;    // bin-center representative
    float tu = tanhf(cf);                   // bin-level tanh (err <= 2.1e-3)
    int t0 = bin_of(cf, gumin, gscale);
    if (bc != 0.f) {
      atomicAdd(&coarse[0 * NB + t0], bc * (1.f - tu));
      atomicAdd(&coarse[1 * NB + t0], bc * tu);
    }
    if (bi != 0.f) {
      atomicAdd(&coarse[2 * NB + t0], bi * (1.f - tu));
      atomicAdd(&coarse[3 * NB + t0], bi * tu);
    }
  }
  __syncthreads();
  if (tid == 0) {
    double ft = df[0], ct = dc[0];
#pragma unroll
    for (int wv = 1; wv < BS / 64; ++wv) { ft += df[wv]; ct += dc[wv]; }
    epilogue(coarse, ft, ct, out, N);
  }
}

extern "C" void kernel_launch(void* const* d_in, const int* in_sizes, int n_in,
                              void* d_out, int out_size, void* d_ws, size_t ws_size,
                              hipStream_t stream) {
  const float* probs = (const float*)d_in[0];
  const float* y     = (const float*)d_in[1];
  const float* w     = (const float*)d_in[2];
  float* out = (float*)d_out;
  int N = in_sizes[0] / C;
  Accum* acc = (Accum*)d_ws;

  init_k<<<1, 256, 0, stream>>>(acc);
  pass1f_k<<<NBLK, BS, 0, stream>>>((const float4*)probs, (const float4*)y,
                                    (const float4*)w, y, acc, out, N);
}

// Round 18
// 36.013 us; speedup vs baseline: 1.7001x; 1.7001x over previous
//
#include <hip/hip_runtime.h>

// AUAvULoss: probs[N,8], y[N,8] one-hot, weights[N,8] -> (avu_loss, CE_loss)
//
// FINAL: R13's algorithm (fixed-range fine histogram over unc, exact
// per-sample tanh; best measured 44.5us) with the reduction tail moved
// behind a KERNEL BOUNDARY. R17 showed the single-kernel retirement-counter
// tail flakes (~1/6) on post-timing re-validation: last block's reads of
// other XCDs' flushes raced (per-XCD L2 non-coherence). Kernel-boundary
// consumption of atomics/partials is the 11-round-flake-free pattern
// (R2-R9). Cost: +~5us vs the flaky single-kernel, fully deterministic.
//
//   init_k  : zero ghist (32 blocks).
//   pass1f_k: stream 96 MB; per-sample entropy/conf/pred via lane-pair
//             scheme; focal/CE/min/max per-block partials; fine hist
//             (512 bins over [0, ln8] — entropy of 8 classes is bounded)
//             in LDS, flushed to ghist[16 replicas] via device atomics.
//             Fine-bin width 4.1e-3 -> only threshold-straddling bins can
//             misassign (~0.15% mass each): dAUC ~2-4e-3 << 4.97e-2 tol;
//             CE/focal exact. (absmax 0.0 measured in R13/R15/R16.)
//   final_k : 1 block, plain loads; exact umin/umax + focal/CE reduce;
//             fine->coarse threshold mapping; trapezoid AUC; outputs.
//
// Falsified perf levers (R4-R16): lane coalescing, stream batching, TLP,
// compute thinning, LDS-atomic replication, occupancy both directions.
// Fatal on MI355X: any in-kernel cross-block waiting (R3: 426us, R12: 154us).

constexpr int C     = 8;
constexpr int NTH   = 21;
constexpr int NB    = 22;       // 0..20 = first threshold satisfied; 21 = none
constexpr int NFINE = 512;      // fine bins over [0, ln8]
constexpr int GREP  = 16;       // global fine-hist replicas
constexpr int NBLK  = 512;
constexpr int BS    = 512;
constexpr float UHI      = 2.0794415416798357f;   // ln(8): entropy upper bound
constexpr float INVW     = (float)NFINE / UHI;
constexpr float BINW     = UHI / (float)NFINE;
constexpr float LOG_FEPS = -18.420680743952367f;  // logf(1e-8f)

struct Accum {
  float f_part[NBLK], c_part[NBLK], mn_part[NBLK], mx_part[NBLK];
  float ghist[GREP][4 * NFINE];
};

__global__ __launch_bounds__(256) void init_k(Accum* acc) {
  int i = blockIdx.x * 256 + threadIdx.x;
  int n = GREP * 4 * NFINE;
  for (; i < n; i += gridDim.x * 256) ((float*)acc->ghist)[i] = 0.f;
}

// Branchless first-satisfied-threshold (same float expr as reference).
__device__ __forceinline__ int bin_of(float u, float umin, float scale) {
  int t0 = NB - 1;
#pragma unroll
  for (int t = NTH - 1; t >= 0; --t) {
    float thr = umin + ((float)t * 0.05f) * scale;
    if (u <= thr) t0 = t;                 // cndmask, no branch
  }
  return t0;
}

__device__ __forceinline__ void epilogue(const float* hist, double fsum, double csum,
                                         float* out, int N) {
  const float *hac = &hist[0], *hau = &hist[NB], *hic = &hist[2 * NB], *hiu = &hist[3 * NB];
  float tot_au = 0.f, tot_iu = 0.f;
  for (int s = 0; s < NB; ++s) { tot_au += hau[s]; tot_iu += hiu[s]; }
  float pac = 0.f, pau = 0.f, pic = 0.f, piu = 0.f, auc = 0.f, prev = 0.f;
  for (int t = 0; t < NTH; ++t) {
    pac += hac[t]; pau += hau[t]; pic += hic[t]; piu += hiu[t];
    float n_ac = pac, n_au = tot_au - pau, n_ic = pic, n_iu = tot_iu - piu;
    float avu = (n_ac + n_iu) / (n_ac + n_au + n_ic + n_iu + 1e-10f);
    if (t > 0) auc += 0.5f * (avu + prev) * 0.05f;
    prev = avu;
  }
  out[0] = -logf(auc + 1e-10f) + (float)(fsum / (double)N);  // BETA = 1
  out[1] = (float)(csum / (double)N);
}

__global__ __launch_bounds__(BS) void pass1f_k(const float4* __restrict__ p4,
                                               const float4* __restrict__ y4,
                                               const float4* __restrict__ w4,
                                               const float*  __restrict__ yraw,
                                               Accum* __restrict__ acc, int N) {
  __shared__ float h[4 * NFINE];            // 8 KB fine hist
  __shared__ int sh_l0;
  for (int i = threadIdx.x; i < 4 * NFINE; i += BS) h[i] = 0.f;
  if (threadIdx.x == 0) {
    float best = yraw[0]; int bi = 0;
#pragma unroll
    for (int j = 1; j < C; ++j) { if (yraw[j] > best) { best = yraw[j]; bi = j; } }
    sh_l0 = bi;
  }
  __syncthreads();
  const int l0   = sh_l0;
  const int tid  = threadIdx.x;
  const int q    = tid & 1;                 // channel half (0: ch0-3, 1: ch4-7)
  const int T    = blockIdx.x * BS + tid;
  const int S    = NBLK * BS;
  const int twoN = 2 * N;                   // f4s per array (even; pairs intact)

  float fsum = 0.f, csum = 0.f;
  float umin = __uint_as_float(0x7F800000u), umax = 0.f;

  for (int idx = T; idx < twoN; idx += S) {
    float4 pv = p4[idx];
    float4 yv = y4[idx];
    float4 wv = w4[idx];
    float P[4] = {pv.x, pv.y, pv.z, pv.w};
    float Y[4] = {yv.x, yv.y, yv.z, yv.w};
    float W[4] = {wv.x, wv.y, wv.z, wv.w};
    float up = 0.f, cep = 0.f, fop = 0.f;
    float cmax = P[0]; int pid = 0;
#pragma unroll
    for (int j = 0; j < 4; ++j) {
      if (j > 0 && P[j] > cmax) { cmax = P[j]; pid = j; }  // first-occurrence
      float le = __logf(fmaxf(P[j], 1e-10f));              // entropy log (EPS=1e-10)
      up -= P[j] * le;
      float lf = fmaxf(le, LOG_FEPS);                      // = log(max(p,1e-8))
      float t  = Y[j] * lf;
      cep -= t; fop -= t * W[j];
    }
    pid += 4 * q;
    fsum += fop; csum += cep;               // each lane adds its own half
    float unc = up + __shfl_xor(up, 1);
    float oc  = __shfl_xor(cmax, 1);
    int   op  = __shfl_xor(pid, 1);
    float lo_c = q ? oc : cmax;  int lo_p = q ? op : pid;
    float hi_c = q ? cmax : oc;  int hi_p = q ? pid : op;
    float conf = (hi_c > lo_c) ? hi_c : lo_c;   // ties -> low half (first occ.)
    int   pred = (hi_c > lo_c) ? hi_p : lo_p;
    umin = fminf(umin, unc); umax = fmaxf(umax, unc);
    if (q == 0) {                           // even lane owns the sample
      bool  corr = (pred == l0);
      float base = corr ? conf : (1.f - conf);
      float tu   = tanhf(unc);              // EXACT per-sample tanh
      int   b    = (int)(unc * INVW); b = b < NFINE - 1 ? b : NFINE - 1;
      int   row  = corr ? 0 : 2;
      atomicAdd(&h[row * NFINE + b],       base * (1.f - tu));
      atomicAdd(&h[(row + 1) * NFINE + b], base * tu);
    }
  }

  {  // per-block partials
    float v0 = fsum, v1 = csum, v2 = umin, v3 = umax;
#pragma unroll
    for (int o = 32; o > 0; o >>= 1) {
      v0 += __shfl_down(v0, o); v1 += __shfl_down(v1, o);
      v2 = fminf(v2, __shfl_down(v2, o)); v3 = fmaxf(v3, __shfl_down(v3, o));
    }
    __shared__ float r0[BS / 64], r1[BS / 64], r2[BS / 64], r3[BS / 64];
    int ln = tid & 63, wd = tid >> 6;
    if (ln == 0) { r0[wd] = v0; r1[wd] = v1; r2[wd] = v2; r3[wd] = v3; }
    __syncthreads();
    if (tid == 0) {
      float a0 = r0[0], a1 = r1[0], a2 = r2[0], a3 = r3[0];
#pragma unroll
      for (int wv = 1; wv < BS / 64; ++wv) {
        a0 += r0[wv]; a1 += r1[wv];
        a2 = fminf(a2, r2[wv]); a3 = fmaxf(a3, r3[wv]);
      }
      acc->f_part[blockIdx.x] = a0;  acc->c_part[blockIdx.x] = a1;
      acc->mn_part[blockIdx.x] = a2; acc->mx_part[blockIdx.x] = a3;
    }
  }
  __syncthreads();
  // flush fine hist (skip zeros) into replicated global hist; consumed only
  // AFTER the kernel boundary (device-wide sync) by final_k.
  for (int i = tid; i < 4 * NFINE; i += BS) {
    float v = h[i];
    if (v != 0.f) atomicAdd(&acc->ghist[blockIdx.x & (GREP - 1)][i], v);
  }
}

__global__ __launch_bounds__(BS) void final_k(const Accum* __restrict__ acc,
                                              float* __restrict__ out, int N) {
  const int tid = threadIdx.x;
  __shared__ float sh_umin, sh_scale;
  __shared__ double df[BS / 64], dc[BS / 64];
  {
    float mn = acc->mn_part[tid];           // NBLK == BS: one partial each
    float mx = acc->mx_part[tid];
    double f = (double)acc->f_part[tid];
    double c = (double)acc->c_part[tid];
#pragma unroll
    for (int o = 32; o > 0; o >>= 1) {
      mn = fminf(mn, __shfl_down(mn, o)); mx = fmaxf(mx, __shfl_down(mx, o));
      f += __shfl_down(f, o);             c += __shfl_down(c, o);
    }
    __shared__ float rmn[BS / 64], rmx[BS / 64];
    int ln = tid & 63, wd = tid >> 6;
    if (ln == 0) { rmn[wd] = mn; rmx[wd] = mx; df[wd] = f; dc[wd] = c; }
    __syncthreads();
    if (tid == 0) {
      float a = rmn[0], b = rmx[0];
#pragma unroll
      for (int wv = 1; wv < BS / 64; ++wv) { a = fminf(a, rmn[wv]); b = fmaxf(b, rmx[wv]); }
      sh_umin = a; sh_scale = b - a;
    }
    __syncthreads();
  }
  const float gumin = sh_umin, gscale = sh_scale;

  // fine -> coarse (each thread owns one fine bin; NFINE == BS)
  __shared__ float coarse[4 * NB];
  if (tid < 4 * NB) coarse[tid] = 0.f;
  __syncthreads();
  {
    int f = tid;
    float v0 = 0.f, v1 = 0.f, v2 = 0.f, v3 = 0.f;
#pragma unroll
    for (int r = 0; r < GREP; ++r) {
      v0 += acc->ghist[r][0 * NFINE + f];
      v1 += acc->ghist[r][1 * NFINE + f];
      v2 += acc->ghist[r][2 * NFINE + f];
      v3 += acc->ghist[r][3 * NFINE + f];
    }
    float cf = ((float)f + 0.5f) * BINW;    // bin-center representative
    int t0 = bin_of(cf, gumin, gscale);
    if (v0 != 0.f) atomicAdd(&coarse[0 * NB + t0], v0);
    if (v1 != 0.f) atomicAdd(&coarse[1 * NB + t0], v1);
    if (v2 != 0.f) atomicAdd(&coarse[2 * NB + t0], v2);
    if (v3 != 0.f) atomicAdd(&coarse[3 * NB + t0], v3);
  }
  __syncthreads();
  if (tid == 0) {
    double ft = df[0], ct = dc[0];
#pragma unroll
    for (int wv = 1; wv < BS / 64; ++wv) { ft += df[wv]; ct += dc[wv]; }
    epilogue(coarse, ft, ct, out, N);
  }
}

extern "C" void kernel_launch(void* const* d_in, const int* in_sizes, int n_in,
                              void* d_out, int out_size, void* d_ws, size_t ws_size,
                              hipStream_t stream) {
  const float* probs = (const float*)d_in[0];
  const float* y     = (const float*)d_in[1];
  const float* w     = (const float*)d_in[2];
  float* out = (float*)d_out;
  int N = in_sizes[0] / C;
  Accum* acc = (Accum*)d_ws;

  init_k<<<32, 256, 0, stream>>>(acc);
  pass1f_k<<<NBLK, BS, 0, stream>>>((const float4*)probs, (const float4*)y,
                                    (const float4*)w, y, acc, N);
  final_k<<<1, BS, 0, stream>>>(acc, out, N);
}